// Round 7
// baseline (70.123 us; speedup 1.0000x reference)
//
#include <hip/hip_runtime.h>

#define BB 1024
#define DD 512
#define BT 64     // batch rows per block
#define JT 128    // j columns per block
#define KT 32     // i depth per block
#define NIC (DD / KT)               // 16 i-chunks
#define NTP ((DD / JT) * NIC)       // 64 t-partials per b
#define NNP (NIC * 4)               // 64 norm-partials per b (ic x wave)
// ws rows: [0,64) t partials, [64,128) norm partials; layout [row][b].

typedef const __attribute__((address_space(1))) void* gptr_t;
typedef __attribute__((address_space(3))) void* lptr_t;

// out[b] = ||x_dot[b]||^2 + t[b]^2,  t[b] = sum_{i,j} x_dot[b,i] W[i,j] x[b,j]
// k1: block (rg,jc,ic) computes the t-partial over its (i,j) rectangle.
// R7 changes: W staged via global_load_lds width=16 (no VGPR round-trip);
// epilogue x prefetched into registers before the barrier (R5's win).
__global__ __launch_bounds__(256, 4) void stm_main_kernel(
    const float* __restrict__ x, const float* __restrict__ xdot,
    const float* __restrict__ W, float* __restrict__ ws_t) {
  __shared__ float xd_t[KT][BT];   // 8 KB, transposed x_dot chunk [i][b]
  __shared__ float w_s[KT * JT];   // 16 KB W tile, flat row-major

  const int tid = threadIdx.x;
  const int b0 = blockIdx.x * BT;
  const int j0 = blockIdx.y * JT;
  const int i0 = blockIdx.z * KT;
  const int tb = tid >> 5;   // 0..7  -> rows b0 + 8*tb .. +7
  const int tj = tid & 31;   // 0..31 -> cols j0 + 4*tj .. +3
  const int wv = tid >> 6, lane = tid & 63;

  // W tile via direct global->LDS DMA. Each 1 KB chunk c = 2 contiguous
  // W rows; lane ln supplies bytes [c*1024 + ln*16 .. +15] (wave-uniform
  // LDS base + lane*16 — the HW-required layout). 4 chunks per wave.
  {
    const int lrow = lane >> 5;            // 0..1
    const int lcol = (lane & 31) * 4;      // 0..124
#pragma unroll
    for (int k = 0; k < 4; ++k) {
      const int c = wv * 4 + k;            // chunk 0..15
      const float* g = W + (size_t)(i0 + 2 * c + lrow) * DD + j0 + lcol;
      __builtin_amdgcn_global_load_lds((gptr_t)g, (lptr_t)&w_s[c * 256],
                                       16, 0, 0);
    }
  }

  // Stage x_dot chunk transposed (row = lane -> conflict-free writes),
  // accumulating this thread's 8 squares for the norm partial.
  float nrm = 0.f;
  {
    const float* src = xdot + (size_t)(b0 + lane) * DD + i0;
#pragma unroll
    for (int p = 0; p < 2; ++p) {
      const int c4 = wv + p * 4;           // 0..7
      const float4 v = *(const float4*)(src + c4 * 4);
      nrm += v.x * v.x + v.y * v.y + v.z * v.z + v.w * v.w;
      const int c = c4 * 4;
      xd_t[c + 0][lane] = v.x; xd_t[c + 1][lane] = v.y;
      xd_t[c + 2][lane] = v.z; xd_t[c + 3][lane] = v.w;
    }
  }
  if (blockIdx.y == 0)   // norm partials: one per (ic, wave)
    ws_t[(size_t)(NTP + blockIdx.z * 4 + wv) * BB + b0 + lane] = nrm;

  // Prefetch epilogue x values; latency overlaps the FMA loop.
  float4 xv[8];
#pragma unroll
  for (int r = 0; r < 8; ++r)
    xv[r] = *(const float4*)(x + (size_t)(b0 + tb * 8 + r) * DD + j0 + tj * 4);

  __syncthreads();   // drains the global_load_lds DMA too (vmcnt)

  // acc[r][c] = sum_i xd[b0+8tb+r, i] * W[i, j0+4tj+c]
  float acc[8][4] = {};
#pragma unroll
  for (int i = 0; i < KT; ++i) {
    const float4 xlo = *(const float4*)&xd_t[i][tb * 8];     // broadcast-ish
    const float4 xhi = *(const float4*)&xd_t[i][tb * 8 + 4];
    const float4 w   = *(const float4*)&w_s[i * JT + tj * 4];
    acc[0][0] += xlo.x * w.x; acc[0][1] += xlo.x * w.y;
    acc[0][2] += xlo.x * w.z; acc[0][3] += xlo.x * w.w;
    acc[1][0] += xlo.y * w.x; acc[1][1] += xlo.y * w.y;
    acc[1][2] += xlo.y * w.z; acc[1][3] += xlo.y * w.w;
    acc[2][0] += xlo.z * w.x; acc[2][1] += xlo.z * w.y;
    acc[2][2] += xlo.z * w.z; acc[2][3] += xlo.z * w.w;
    acc[3][0] += xlo.w * w.x; acc[3][1] += xlo.w * w.y;
    acc[3][2] += xlo.w * w.z; acc[3][3] += xlo.w * w.w;
    acc[4][0] += xhi.x * w.x; acc[4][1] += xhi.x * w.y;
    acc[4][2] += xhi.x * w.z; acc[4][3] += xhi.x * w.w;
    acc[5][0] += xhi.y * w.x; acc[5][1] += xhi.y * w.y;
    acc[5][2] += xhi.y * w.z; acc[5][3] += xhi.y * w.w;
    acc[6][0] += xhi.z * w.x; acc[6][1] += xhi.z * w.y;
    acc[6][2] += xhi.z * w.z; acc[6][3] += xhi.z * w.w;
    acc[7][0] += xhi.w * w.x; acc[7][1] += xhi.w * w.y;
    acc[7][2] += xhi.w * w.z; acc[7][3] += xhi.w * w.w;
  }

  // Contract with prefetched x, reduce over the 32 tj lanes.
  float tp[8];
#pragma unroll
  for (int r = 0; r < 8; ++r)
    tp[r] = acc[r][0] * xv[r].x + acc[r][1] * xv[r].y +
            acc[r][2] * xv[r].z + acc[r][3] * xv[r].w;
#pragma unroll
  for (int off = 16; off >= 1; off >>= 1) {
#pragma unroll
    for (int r = 0; r < 8; ++r) tp[r] += __shfl_xor(tp[r], off);
  }
  if (tj == 0) {
    const int p = blockIdx.y * NIC + blockIdx.z;   // 0..63
    float* dst = ws_t + (size_t)p * BB + b0 + tb * 8;
    *(float4*)(dst + 0) = make_float4(tp[0], tp[1], tp[2], tp[3]);
    *(float4*)(dst + 4) = make_float4(tp[4], tp[5], tp[6], tp[7]);
  }
}

// k2: one thread per b. out[b] = (sum norm partials) + (sum t partials)^2.
__global__ __launch_bounds__(256) void stm_final_kernel(
    const float* __restrict__ ws_t, float* __restrict__ out) {
  const int b = blockIdx.x * 256 + threadIdx.x;
  float t = 0.f, n = 0.f;
#pragma unroll
  for (int p = 0; p < NTP; ++p) t += ws_t[(size_t)p * BB + b];
#pragma unroll
  for (int p = 0; p < NNP; ++p) n += ws_t[(size_t)(NTP + p) * BB + b];
  out[b] = n + t * t;
}

extern "C" void kernel_launch(void* const* d_in, const int* in_sizes, int n_in,
                              void* d_out, int out_size, void* d_ws, size_t ws_size,
                              hipStream_t stream) {
  const float* x    = (const float*)d_in[0];
  const float* xdot = (const float*)d_in[1];
  const float* W    = (const float*)d_in[2];
  float* ws = (float*)d_ws;   // 128 * 1024 floats = 512 KB of partials
  float* out = (float*)d_out;

  dim3 g1(BB / BT, DD / JT, NIC);  // (16, 4, 16) = 1024 blocks
  stm_main_kernel<<<g1, 256, 0, stream>>>(x, xdot, W, ws);
  stm_final_kernel<<<BB / 256, 256, 0, stream>>>(ws, out);
}

// Round 8
// 69.294 us; speedup vs baseline: 1.0120x; 1.0120x over previous
//
#include <hip/hip_runtime.h>

#define BB 1024
#define DD 512
#define BTILE 32     // batch rows per block
#define JTILE 128    // j columns per block
#define ICH 64       // i depth per block
#define NIC (DD / ICH)              // 8 i-chunks
#define NTP ((DD / JTILE) * NIC)    // 32 t-partials per b
#define NNP (NIC * 4)               // 32 norm-partials per b (ic x wave)
// ws layout: rows 0..31 = t partials, rows 32..63 = norm partials; [row][b].

// out[b] = ||x_dot[b]||^2 + t[b]^2,  t[b] = sum_{i,j} x_dot[b,i] W[i,j] x[b,j]
// Best-measured variant (R5, 68.73 us). Session evidence (R5/R6/R7): k1's
// LDS intensity, DMA staging, and tiling are all within noise — the timed
// window is dominated by the harness's 256 MiB d_ws re-poison fill
// (~40.5 us at the 6.3 TB/s achievable-HBM roofline) + input restores.
__global__ __launch_bounds__(256, 4) void stm_main_kernel(
    const float* __restrict__ x, const float* __restrict__ xdot,
    const float* __restrict__ W, float* __restrict__ ws_t) {
  __shared__ float xd_t[ICH][BTILE];   // 8 KB, transposed x_dot chunk [i][b]
  __shared__ float w_s[ICH][JTILE];    // 32 KB W tile

  const int tid = threadIdx.x;
  const int b0 = blockIdx.x * BTILE;
  const int j0 = blockIdx.y * JTILE;
  const int i0 = blockIdx.z * ICH;
  const int tb = tid >> 5;   // 0..7  -> rows b0 + 4*tb .. +3
  const int tj = tid & 31;   // 0..31 -> cols j0 + 4*tj .. +3

  // Stage x_dot chunk transposed: rows b0..b0+31, cols i0..i0+63.
  // Also accumulate this thread's 8 squared elements for the norm.
  float nrm = 0.f;
  {
    const int row = tid & 31;
    const int f4 = tid >> 5;             // 0..7
    const float4* src = (const float4*)(xdot + (size_t)(b0 + row) * DD + i0);
#pragma unroll
    for (int p = 0; p < 2; ++p) {
      const int c4 = f4 + p * 8;         // 0..15
      float4 v = src[c4];
      nrm += v.x * v.x + v.y * v.y + v.z * v.z + v.w * v.w;
      const int c = c4 * 4;
      xd_t[c + 0][row] = v.x; xd_t[c + 1][row] = v.y;
      xd_t[c + 2][row] = v.z; xd_t[c + 3][row] = v.w;
    }
  }
  // Stage W tile: rows i0..i0+63, cols j0..j0+127 (2048 float4 / 256 thr).
  {
#pragma unroll
    for (int v = 0; v < 8; ++v) {
      const int f4 = tid + v * 256;
      const int ii = f4 >> 5, jj4 = f4 & 31;
      *((float4*)&w_s[ii][jj4 * 4]) =
          ((const float4*)(W + (size_t)(i0 + ii) * DD + j0))[jj4];
    }
  }

  // Norm partials: lanes l and l+32 cover the same row with disjoint column
  // halves -> one xor-32 fold; wave w stores rows 0..31. jc==0 blocks only.
  if (blockIdx.y == 0) {
    nrm += __shfl_xor(nrm, 32);
    const int wv = tid >> 6, ln = tid & 63;
    if (ln < 32)
      ws_t[(size_t)(NTP + blockIdx.z * 4 + wv) * BB + b0 + ln] = nrm;
  }

  // Prefetch epilogue x values so their latency overlaps the FMA loop.
  float4 xv[4];
#pragma unroll
  for (int r = 0; r < 4; ++r)
    xv[r] = ((const float4*)(x + (size_t)(b0 + tb * 4 + r) * DD + j0))[tj];

  __syncthreads();

  // acc[r][c] = sum_i xd[b0+4tb+r, i] * W[i, j0+4tj+c]
  float acc[4][4] = {};
#pragma unroll
  for (int i = 0; i < ICH; ++i) {
    const float4 xd = *(const float4*)&xd_t[i][tb * 4];  // 8 uniq addrs/wave
    const float4 w  = *(const float4*)&w_s[i][tj * 4];
    acc[0][0] += xd.x * w.x; acc[0][1] += xd.x * w.y;
    acc[0][2] += xd.x * w.z; acc[0][3] += xd.x * w.w;
    acc[1][0] += xd.y * w.x; acc[1][1] += xd.y * w.y;
    acc[1][2] += xd.y * w.z; acc[1][3] += xd.y * w.w;
    acc[2][0] += xd.z * w.x; acc[2][1] += xd.z * w.y;
    acc[2][2] += xd.z * w.z; acc[2][3] += xd.z * w.w;
    acc[3][0] += xd.w * w.x; acc[3][1] += xd.w * w.y;
    acc[3][2] += xd.w * w.z; acc[3][3] += xd.w * w.w;
  }

  // Contract with prefetched x, reduce over the 32 tj lanes.
  float tp[4];
#pragma unroll
  for (int r = 0; r < 4; ++r)
    tp[r] = acc[r][0] * xv[r].x + acc[r][1] * xv[r].y +
            acc[r][2] * xv[r].z + acc[r][3] * xv[r].w;
#pragma unroll
  for (int off = 16; off >= 1; off >>= 1) {
#pragma unroll
    for (int r = 0; r < 4; ++r) tp[r] += __shfl_xor(tp[r], off);
  }
  if (tj == 0) {
    const int p = blockIdx.y * NIC + blockIdx.z;   // 0..31
    *(float4*)(ws_t + (size_t)p * BB + b0 + tb * 4) =
        make_float4(tp[0], tp[1], tp[2], tp[3]);
  }
}

// k2: one thread per b. out[b] = (sum norm partials) + (sum t partials)^2.
// 256 KB of partials, L2-resident, fully coalesced across b.
__global__ __launch_bounds__(256) void stm_final_kernel(
    const float* __restrict__ ws_t, float* __restrict__ out) {
  const int b = blockIdx.x * 256 + threadIdx.x;
  float t = 0.f, n = 0.f;
#pragma unroll
  for (int p = 0; p < NTP; ++p) t += ws_t[(size_t)p * BB + b];
#pragma unroll
  for (int p = 0; p < NNP; ++p) n += ws_t[(size_t)(NTP + p) * BB + b];
  out[b] = n + t * t;
}

extern "C" void kernel_launch(void* const* d_in, const int* in_sizes, int n_in,
                              void* d_out, int out_size, void* d_ws, size_t ws_size,
                              hipStream_t stream) {
  const float* x    = (const float*)d_in[0];
  const float* xdot = (const float*)d_in[1];
  const float* W    = (const float*)d_in[2];
  float* ws = (float*)d_ws;   // 64 * 1024 floats = 256 KB of partials
  float* out = (float*)d_out;

  dim3 g1(BB / BTILE, DD / JTILE, NIC);  // (32, 4, 8) = 1024 blocks
  stm_main_kernel<<<g1, 256, 0, stream>>>(x, xdot, W, ws);
  stm_final_kernel<<<BB / 256, 256, 0, stream>>>(ws, out);
}